// Round 4
// baseline (510.489 us; speedup 1.0000x reference)
//
#include <hip/hip_runtime.h>
#include <math.h>

#define D_MODEL 1024
#define NHEAD   16
#define HDIM    64
#define SEQ     2048
#define BATCH   2
#define NROWS   (BATCH*SEQ)   // 4096

typedef unsigned short u16;
typedef __attribute__((ext_vector_type(8))) short short8;
typedef __attribute__((ext_vector_type(4))) float f32x4;

// ---- bf16 helpers ----
__device__ __forceinline__ u16 f2bf(float x) {           // RNE
    unsigned int u = __float_as_uint(x);
    u += 0x7fffu + ((u >> 16) & 1u);
    return (u16)(u >> 16);
}
__device__ __forceinline__ u16 f2bf_trunc(float x) {     // truncate (1 op)
    return (u16)(__float_as_uint(x) >> 16);
}
__device__ __forceinline__ float bf2f(u16 h) {
    return __uint_as_float(((unsigned int)h) << 16);
}

// ---------------------------------------------------------------- gdiag
// gdiag[h,d] = (sum_i A[h,i,d]^2 + exp(log_lambda[h])) * log2(e)
__global__ void gdiag_kernel(const float* __restrict__ A,
                             const float* __restrict__ log_lambda,
                             float* __restrict__ gdiag) {
    int id = blockIdx.x * 256 + threadIdx.x;
    if (id >= NHEAD * HDIM) return;
    int h = id >> 6, d = id & 63;
    float s = 0.f;
#pragma unroll
    for (int i = 0; i < 16; ++i) {
        float a = A[(h * 16 + i) * HDIM + d];
        s += a * a;
    }
    gdiag[id] = (s + __expf(log_lambda[h])) * 1.4426950408889634f;
}

// ---------------------------------------------------------------- prep: fp32 -> bf16 hi/lo
__global__ void prep_split(const float* __restrict__ x,
                           const float* __restrict__ Wq, const float* __restrict__ Wk,
                           const float* __restrict__ Wv, const float* __restrict__ Wo,
                           u16* __restrict__ xh, u16* __restrict__ xl,
                           u16* __restrict__ wqh, u16* __restrict__ wql,
                           u16* __restrict__ wkh, u16* __restrict__ wkl,
                           u16* __restrict__ wvh, u16* __restrict__ woh) {
    int seg = blockIdx.y;
    int i = blockIdx.x * 256 + threadIdx.x;   // float4 index
    const float* src; u16* dh; u16* dl; int n4;
    if      (seg == 0) { src = x;  dh = xh;  dl = xl;      n4 = NROWS * D_MODEL / 4; }
    else if (seg == 1) { src = Wq; dh = wqh; dl = wql;     n4 = D_MODEL * D_MODEL / 4; }
    else if (seg == 2) { src = Wk; dh = wkh; dl = wkl;     n4 = D_MODEL * D_MODEL / 4; }
    else if (seg == 3) { src = Wv; dh = wvh; dl = nullptr; n4 = D_MODEL * D_MODEL / 4; }
    else               { src = Wo; dh = woh; dl = nullptr; n4 = D_MODEL * D_MODEL / 4; }
    if (i >= n4) return;
    float4 v = *(const float4*)&src[(size_t)i * 4];
    float vv[4] = {v.x, v.y, v.z, v.w};
    u16 hv[4], lv[4];
#pragma unroll
    for (int j = 0; j < 4; ++j) {
        u16 hb = f2bf(vv[j]);
        hv[j] = hb;
        lv[j] = f2bf(vv[j] - bf2f(hb));
    }
    *(uint2*)&dh[(size_t)i * 4] = *(uint2*)hv;
    if (dl) *(uint2*)&dl[(size_t)i * 4] = *(uint2*)lv;
}

// ---------------------------------------------------------------- zero-LDS direct MFMA GEMM
// out[r][c] = sum_k A[r][k]*W[c][k] + bias[c]; A,W bf16 hi(/lo) row-major [*, 1024].
// Block 128x128 = 2x2 waves of 64x64. All fragments load global->register with
// one-iteration prefetch double-buffer. No LDS, no barriers.
template<int NP3>
struct Frag {
    short8 ah[4], bh[4];
    short8 al[NP3 ? 4 : 1], bl[NP3 ? 4 : 1];
};

template<int NP3>
__global__ __launch_bounds__(256)
void gemm_direct(const u16* __restrict__ Ahp, const u16* __restrict__ Alp,
                 const u16* __restrict__ Bh0, const u16* __restrict__ Bl0, const float* __restrict__ bias0,
                 float* outf0, u16* auxh0, u16* auxl0, float* ks0,
                 const u16* __restrict__ Bh1, const u16* __restrict__ Bl1, const float* __restrict__ bias1,
                 float* outf1, u16* auxh1, u16* auxl1, float* ks1,
                 int out_layout) {
    const int z = blockIdx.z;
    const u16* Bh = (z == 0) ? Bh0 : Bh1;
    const u16* Bl = (z == 0) ? Bl0 : Bl1;
    const float* bias = (z == 0) ? bias0 : bias1;
    float* outf = (z == 0) ? outf0 : outf1;
    u16* auxh   = (z == 0) ? auxh0 : auxh1;
    u16* auxl   = (z == 0) ? auxl0 : auxl1;
    float* ksump= (z == 0) ? ks0 : ks1;

    const int tid = threadIdx.x;
    const int w = tid >> 6, lane = tid & 63, quad = lane >> 4, n16 = lane & 15;
    const int rw = blockIdx.y * 128 + (w & 1) * 64;
    const int cw = blockIdx.x * 128 + (w >> 1) * 64;

    f32x4 acc[4][4] = {};
    Frag<NP3> fA, fB;

    auto ld = [&](Frag<NP3>& f, int kt) {
        kt &= (D_MODEL - 1);
        int ko = kt + quad * 8;
#pragma unroll
        for (int mt = 0; mt < 4; ++mt) {
            size_t ro = (size_t)(rw + mt * 16 + n16) * D_MODEL + ko;
            f.ah[mt] = *(const short8*)&Ahp[ro];
            if (NP3) f.al[mt] = *(const short8*)&Alp[ro];
        }
#pragma unroll
        for (int nt = 0; nt < 4; ++nt) {
            size_t co = (size_t)(cw + nt * 16 + n16) * D_MODEL + ko;
            f.bh[nt] = *(const short8*)&Bh[co];
            if (NP3) f.bl[nt] = *(const short8*)&Bl[co];
        }
    };
    auto cmp = [&](Frag<NP3>& f) {
#pragma unroll
        for (int nt = 0; nt < 4; ++nt)
#pragma unroll
            for (int mt = 0; mt < 4; ++mt) {
                acc[mt][nt] = __builtin_amdgcn_mfma_f32_16x16x32_bf16(f.ah[mt], f.bh[nt], acc[mt][nt], 0, 0, 0);
                if (NP3) {
                    acc[mt][nt] = __builtin_amdgcn_mfma_f32_16x16x32_bf16(f.ah[mt], f.bl[nt], acc[mt][nt], 0, 0, 0);
                    acc[mt][nt] = __builtin_amdgcn_mfma_f32_16x16x32_bf16(f.al[mt], f.bh[nt], acc[mt][nt], 0, 0, 0);
                }
            }
    };

    ld(fA, 0);
    for (int i2 = 0; i2 < 16; ++i2) {
        ld(fB, i2 * 64 + 32);
        cmp(fA);
        ld(fA, i2 * 64 + 64);   // overshoot wraps via &(D_MODEL-1); final load unused
        cmp(fB);
    }

    // epilogue: C row = quad*4+reg, col = n16 within each 16x16 tile
    float csum[4] = {0.f, 0.f, 0.f, 0.f};
#pragma unroll
    for (int mt = 0; mt < 4; ++mt) {
#pragma unroll
        for (int nt = 0; nt < 4; ++nt) {
            int c = cw + nt * 16 + n16;
            float bc = bias[c];
            int rb = rw + mt * 16 + quad * 4;
#pragma unroll
            for (int reg = 0; reg < 4; ++reg) {
                float val = acc[mt][nt][reg] + bc;
                int rr = rb + reg;
                size_t idx = out_layout
                    ? ((size_t)(((rr >> 11) * NHEAD + (c >> 6)) * SEQ + (rr & (SEQ - 1)))) * HDIM + (c & 63)
                    : (size_t)rr * D_MODEL + c;
                if (outf) outf[idx] = val;
                if (auxh) {
                    u16 hb = f2bf(val);
                    auxh[idx] = hb;
                    if (auxl) auxl[idx] = f2bf(val - bf2f(hb));
                }
                csum[nt] += val;
            }
        }
    }
    if (ksump) {
#pragma unroll
        for (int nt = 0; nt < 4; ++nt) {
            float cs = csum[nt];
            cs += __shfl_xor(cs, 16);
            cs += __shfl_xor(cs, 32);
            if (quad == 0) {
                int c = cw + nt * 16 + n16;
                atomicAdd(&ksump[((rw >> 11) * NHEAD + (c >> 6)) * HDIM + (c & 63)], cs);
            }
        }
    }
}

// ---------------------------------------------------------------- v transpose: (b,h,t,hd) bf16 -> (b,h,hd,t)
__global__ __launch_bounds__(256)
void vtrans_kernel(const u16* __restrict__ vh, u16* __restrict__ vT) {
    __shared__ __align__(16) u16 tile[64][72];
    const int tid = threadIdx.x;
    const int t0 = blockIdx.x * 64;
    const int bh = blockIdx.y;
    const u16* vp = vh + (size_t)bh * SEQ * HDIM;
#pragma unroll
    for (int s = 0; s < 2; ++s) {
        int id = s * 256 + tid;
        int row = id >> 3, c8 = (id & 7) * 8;
        *(short8*)&tile[row][c8] = *(const short8*)&vp[(size_t)(t0 + row) * HDIM + c8];
    }
    __syncthreads();
#pragma unroll
    for (int s = 0; s < 2; ++s) {
        int id = s * 256 + tid;
        int d = id >> 3, t8 = (id & 7) * 8;
        short8 r;
#pragma unroll
        for (int i = 0; i < 8; ++i) r[i] = (short)tile[t8 + i][d];
        *(short8*)&vT[((size_t)bh * HDIM + d) * SEQ + t0 + t8] = r;
    }
}

// ---------------------------------------------------------------- flash attention v5: two-pass, j-split
// Pass 1: hi-only QK^T -> per-row max (register fmax, one shfl reduce, LDS merge -> block M).
// Pass 2: fixed-M softmax (no online rescale, fully independent iterations), 3-pass split QK,
// p via per-wave LDS round-trip, PV + l via ones-MFMA accumulators. Prefetched K frags.
__global__ __launch_bounds__(256)
void flash_v5(const float* __restrict__ q, const u16* __restrict__ kh,
              const u16* __restrict__ kl, const u16* __restrict__ vT,
              const float* __restrict__ ksum, const float* __restrict__ gdiag,
              u16* __restrict__ o) {
    __shared__ __align__(16) u16 ps_all[4 * 64 * 40];   // per-wave p tiles; reused as Os[64][68] f32
    __shared__ float Mw[4][64];
    __shared__ float Lw[4][64];

    const int tid = threadIdx.x;
    const int w = tid >> 6, lane = tid & 63, quad = lane >> 4, n16 = lane & 15;
    const int t0 = blockIdx.x * 64;
    const int h = blockIdx.y, b = blockIdx.z;
    const size_t bh = (size_t)b * NHEAD + h;
    const float* qp = q + bh * SEQ * HDIM;
    const u16* khp = kh + bh * SEQ * HDIM;
    const u16* klp = kl + bh * SEQ * HDIM;
    const u16* vtp = vT + bh * HDIM * SEQ;
    u16* psw = ps_all + w * 64 * 40;

    // ---- Sg A-fragments (hi/lo): all 64 rows x 64 dims; A[m=n16][k=quad*8+j] ----
    short8 sgh[4][2], sgl[4][2];
#pragma unroll
    for (int mt = 0; mt < 4; ++mt) {
#pragma unroll
        for (int kc = 0; kc < 2; ++kc) {
            int row = t0 + mt * 16 + n16;
            int d0 = kc * 32 + quad * 8;
            float4 q0 = *(const float4*)&qp[(size_t)row * HDIM + d0];
            float4 q1 = *(const float4*)&qp[(size_t)row * HDIM + d0 + 4];
            float4 k0 = *(const float4*)&ksum[bh * HDIM + d0];
            float4 k1 = *(const float4*)&ksum[bh * HDIM + d0 + 4];
            float4 g0 = *(const float4*)&gdiag[(size_t)h * HDIM + d0];
            float4 g1 = *(const float4*)&gdiag[(size_t)h * HDIM + d0 + 4];
            float sg[8];
            sg[0] = (2048.f * q0.x - k0.x) * g0.x; sg[1] = (2048.f * q0.y - k0.y) * g0.y;
            sg[2] = (2048.f * q0.z - k0.z) * g0.z; sg[3] = (2048.f * q0.w - k0.w) * g0.w;
            sg[4] = (2048.f * q1.x - k1.x) * g1.x; sg[5] = (2048.f * q1.y - k1.y) * g1.y;
            sg[6] = (2048.f * q1.z - k1.z) * g1.z; sg[7] = (2048.f * q1.w - k1.w) * g1.w;
#pragma unroll
            for (int j = 0; j < 8; ++j) {
                u16 hb = f2bf(sg[j]);
                sgh[mt][kc][j] = (short)hb;
                sgl[mt][kc][j] = (short)f2bf(sg[j] - bf2f(hb));
            }
        }
    }

    float mx[16];
#pragma unroll
    for (int i = 0; i < 16; ++i) mx[i] = -INFINITY;

    // ================= PASS 1: row max (hi-only QK) =================
    {
        struct KF { short8 kh[2][2]; };
        KF kA, kB;
        auto ldK = [&](KF& f, int it) {
            int jw = ((it & 15) * 128) + w * 32;
#pragma unroll
            for (int kc = 0; kc < 2; ++kc)
#pragma unroll
                for (int ntj = 0; ntj < 2; ++ntj)
                    f.kh[kc][ntj] = *(const short8*)&khp[(size_t)(jw + ntj * 16 + n16) * HDIM + kc * 32 + quad * 8];
        };
        auto body = [&](KF& f) {
            f32x4 lg[2][4] = {};
#pragma unroll
            for (int kc = 0; kc < 2; ++kc)
#pragma unroll
                for (int ntj = 0; ntj < 2; ++ntj)
#pragma unroll
                    for (int mt = 0; mt < 4; ++mt)
                        lg[ntj][mt] = __builtin_amdgcn_mfma_f32_16x16x32_bf16(sgh[mt][kc], f.kh[kc][ntj], lg[ntj][mt], 0, 0, 0);
#pragma unroll
            for (int ntj = 0; ntj < 2; ++ntj)
#pragma unroll
                for (int mt = 0; mt < 4; ++mt)
#pragma unroll
                    for (int r = 0; r < 4; ++r)
                        mx[mt * 4 + r] = fmaxf(mx[mt * 4 + r], lg[ntj][mt][r]);
        };
        ldK(kA, 0);
        for (int i2 = 0; i2 < 8; ++i2) {
            ldK(kB, i2 * 2 + 1);
            body(kA);
            ldK(kA, i2 * 2 + 2);   // wraps at 16 -> harmless unused load
            body(kB);
        }
    }

    // ---- merge row max across lanes and waves -> block-common M ----
#pragma unroll
    for (int i = 0; i < 16; ++i) {
        float v = mx[i];
        v = fmaxf(v, __shfl_xor(v, 1));
        v = fmaxf(v, __shfl_xor(v, 2));
        v = fmaxf(v, __shfl_xor(v, 4));
        v = fmaxf(v, __shfl_xor(v, 8));
        mx[i] = v;
    }
    if (n16 == 0) {
#pragma unroll
        for (int mt = 0; mt < 4; ++mt)
#pragma unroll
            for (int r = 0; r < 4; ++r)
                Mw[w][mt * 16 + quad * 4 + r] = mx[mt * 4 + r];
    }
    __syncthreads();
#pragma unroll
    for (int mt = 0; mt < 4; ++mt)
#pragma unroll
        for (int r = 0; r < 4; ++r) {
            int m = mt * 16 + quad * 4 + r;
            mx[mt * 4 + r] = fmaxf(fmaxf(Mw[0][m], Mw[1][m]), fmaxf(Mw[2][m], Mw[3][m]));
        }

    // ================= PASS 2: fixed-M softmax + PV =================
    f32x4 oacc[4][4] = {};   // [mt][ntd]
    f32x4 lacc[4] = {};      // l via ones-MFMA accumulation
    short8 ones;
#pragma unroll
    for (int j = 0; j < 8; ++j) ones[j] = (short)0x3F80;

    {
        struct KF2 { short8 kh[2][2], kl[2][2]; };
        KF2 kA, kB;
        auto ldK2 = [&](KF2& f, int it) {
            int jw = ((it & 15) * 128) + w * 32;
#pragma unroll
            for (int kc = 0; kc < 2; ++kc)
#pragma unroll
                for (int ntj = 0; ntj < 2; ++ntj) {
                    size_t off = (size_t)(jw + ntj * 16 + n16) * HDIM + kc * 32 + quad * 8;
                    f.kh[kc][ntj] = *(const short8*)&khp[off];
                    f.kl[kc][ntj] = *(const short8*)&klp[off];
                }
        };
        auto body = [&](KF2& f, int it) {
            int jw = it * 128 + w * 32;
            short8 bv[4];
#pragma unroll
            for (int ntd = 0; ntd < 4; ++ntd)
                bv[ntd] = *(const short8*)&vtp[(size_t)(ntd * 16 + n16) * SEQ + jw + quad * 8];
            f32x4 lg[2][4] = {};
#pragma unroll
            for (int kc = 0; kc < 2; ++kc)
#pragma unroll
                for (int ntj = 0; ntj < 2; ++ntj)
#pragma unroll
                    for (int mt = 0; mt < 4; ++mt) {
                        lg[ntj][mt] = __builtin_amdgcn_mfma_f32_16x16x32_bf16(sgh[mt][kc], f.kh[kc][ntj], lg[ntj][mt], 0, 0, 0);
                        lg[ntj][mt] = __builtin_amdgcn_mfma_f32_16x16x32_bf16(sgh[mt][kc], f.kl[kc][ntj], lg[ntj][mt], 0, 0, 0);
                        lg[ntj][mt] = __builtin_amdgcn_mfma_f32_16x16x32_bf16(sgl[mt][kc], f.kh[kc][ntj], lg[ntj][mt], 0, 0, 0);
                    }
            // p = exp2(lg - M); fully independent, no running state
#pragma unroll
            for (int mt = 0; mt < 4; ++mt)
#pragma unroll
                for (int r = 0; r < 4; ++r) {
                    float M = mx[mt * 4 + r];
                    float p0 = exp2f(lg[0][mt][r] - M);
                    float p1 = exp2f(lg[1][mt][r] - M);
                    int m = mt * 16 + quad * 4 + r;
                    psw[m * 40 + n16]      = f2bf_trunc(p0);
                    psw[m * 40 + 16 + n16] = f2bf_trunc(p1);
                }
            // PV + l (same-wave DS write->read is in-order)
#pragma unroll
            for (int mt = 0; mt < 4; ++mt) {
                short8 pa = *(const short8*)&psw[(mt * 16 + n16) * 40 + quad * 8];
                lacc[mt] = __builtin_amdgcn_mfma_f32_16x16x32_bf16(pa, ones, lacc[mt], 0, 0, 0);
#pragma unroll
                for (int ntd = 0; ntd < 4; ++ntd)
                    oacc[mt][ntd] = __builtin_amdgcn_mfma_f32_16x16x32_bf16(pa, bv[ntd], oacc[mt][ntd], 0, 0, 0);
            }
        };
        ldK2(kA, 0);
        for (int i2 = 0; i2 < 8; ++i2) {
            ldK2(kB, i2 * 2 + 1);
            body(kA, i2 * 2);
            ldK2(kA, i2 * 2 + 2);   // wraps at 16 -> harmless unused load
            body(kB, i2 * 2 + 1);
        }
    }

    // ---- merge waves: common M so plain sums ----
    if (n16 == 0) {
#pragma unroll
        for (int mt = 0; mt < 4; ++mt)
#pragma unroll
            for (int r = 0; r < 4; ++r)
                Lw[w][mt * 16 + quad * 4 + r] = lacc[mt][r];
    }
    __syncthreads();   // Lw ready; all psw reads done (safe to alias Os)

    float* Os = (float*)ps_all;   // [64][68]
#pragma unroll
    for (int ww = 0; ww < 4; ++ww) {
        if (w == ww) {
#pragma unroll
            for (int mt = 0; mt < 4; ++mt)
#pragma unroll
                for (int ntd = 0; ntd < 4; ++ntd)
#pragma unroll
                    for (int r = 0; r < 4; ++r) {
                        int m = mt * 16 + quad * 4 + r;
                        int c = ntd * 16 + n16;
                        if (ww == 0) Os[m * 68 + c] = oacc[mt][ntd][r];
                        else         Os[m * 68 + c] += oacc[mt][ntd][r];
                    }
        }
        __syncthreads();
    }

    // ---- normalize + write bf16 (b, t, h*64+d) ----
    {
        int orow = tid >> 2;
        int c0 = (tid & 3) * 16;
        float inv = 1.f / (((Lw[0][orow] + Lw[1][orow]) + (Lw[2][orow] + Lw[3][orow])));
        u16 outv[16];
#pragma unroll
        for (int cc = 0; cc < 16; ++cc)
            outv[cc] = f2bf(Os[orow * 68 + c0 + cc] * inv);
        u16* dst = o + ((size_t)(b * SEQ + t0 + orow)) * D_MODEL + h * HDIM + c0;
        *(uint4*)dst = *(uint4*)outv;
        *(uint4*)(dst + 8) = *(uint4*)(outv + 8);
    }
}

// ---------------------------------------------------------------- launcher
extern "C" void kernel_launch(void* const* d_in, const int* in_sizes, int n_in,
                              void* d_out, int out_size, void* d_ws, size_t ws_size,
                              hipStream_t stream) {
    const float* x  = (const float*)d_in[0];
    const float* Wq = (const float*)d_in[1];
    const float* bq = (const float*)d_in[2];
    const float* Wk = (const float*)d_in[3];
    const float* bk = (const float*)d_in[4];
    const float* Wv = (const float*)d_in[5];
    const float* bv = (const float*)d_in[6];
    const float* Wo = (const float*)d_in[7];
    const float* bo = (const float*)d_in[8];
    const float* A  = (const float*)d_in[9];
    const float* ll = (const float*)d_in[10];
    float* out = (float*)d_out;

    const size_t NQKV = (size_t)NROWS * D_MODEL;   // 4,194,304
    const size_t NW = (size_t)D_MODEL * D_MODEL;   // 1,048,576
    char* base = (char*)d_ws;
    float* q_ws = (float*)base;            base += NQKV * 4;
    u16* xh  = (u16*)base;                 base += NQKV * 2;   // reused as o_hi after QKV
    u16* xl  = (u16*)base;                 base += NQKV * 2;   // reused as vT after QKV
    u16* khw = (u16*)base;                 base += NQKV * 2;
    u16* klw = (u16*)base;                 base += NQKV * 2;
    u16* vhw = (u16*)base;                 base += NQKV * 2;
    u16* wqh = (u16*)base;                 base += NW * 2;
    u16* wql = (u16*)base;                 base += NW * 2;
    u16* wkh = (u16*)base;                 base += NW * 2;
    u16* wkl = (u16*)base;                 base += NW * 2;
    u16* wvh = (u16*)base;                 base += NW * 2;
    u16* woh = (u16*)base;                 base += NW * 2;
    float* gd_ws   = (float*)base;         base += NHEAD * HDIM * 4;
    float* ksum_ws = (float*)base;         base += BATCH * NHEAD * HDIM * 4;

    hipMemsetAsync(ksum_ws, 0, BATCH * NHEAD * HDIM * sizeof(float), stream);

    prep_split<<<dim3(4096, 5), 256, 0, stream>>>(x, Wq, Wk, Wv, Wo,
                                                  xh, xl, wqh, wql, wkh, wkl, wvh, woh);
    gdiag_kernel<<<4, 256, 0, stream>>>(A, ll, gd_ws);

    // Q (z=0) + K (z=1): 3-pass split-bf16; K writes k_hi/k_lo + ksum atomics
    gemm_direct<1><<<dim3(8, 32, 2), 256, 0, stream>>>(
        xh, xl,
        wqh, wql, bq, q_ws, nullptr, nullptr, nullptr,
        wkh, wkl, bk, nullptr, khw, klw, ksum_ws,
        1);
    // V: 1-pass bf16, bf16 output
    gemm_direct<0><<<dim3(8, 32, 1), 256, 0, stream>>>(
        xh, nullptr,
        wvh, nullptr, bv, nullptr, vhw, nullptr, nullptr,
        wvh, nullptr, bv, nullptr, vhw, nullptr, nullptr,
        1);

    u16* vTw = xl;   // alias: x_lo dead after QKV GEMMs
    u16* ohw = xh;   // alias: x_hi dead after QKV GEMMs
    vtrans_kernel<<<dim3(SEQ / 64, BATCH * NHEAD), 256, 0, stream>>>(vhw, vTw);

    flash_v5<<<dim3(SEQ / 64, NHEAD, BATCH), 256, 0, stream>>>(
        q_ws, khw, klw, vTw, ksum_ws, gd_ws, ohw);

    // out-proj: 1-pass bf16, row-major fp32 output
    gemm_direct<0><<<dim3(8, 32, 1), 256, 0, stream>>>(
        ohw, nullptr,
        woh, nullptr, bo, out, nullptr, nullptr, nullptr,
        woh, nullptr, bo, out, nullptr, nullptr, nullptr,
        0);
}

// Round 5
// 430.197 us; speedup vs baseline: 1.1866x; 1.1866x over previous
//
#include <hip/hip_runtime.h>
#include <math.h>

#define D_MODEL 1024
#define NHEAD   16
#define HDIM    64
#define SEQ     2048
#define BATCH   2
#define NROWS   (BATCH*SEQ)   // 4096

typedef unsigned short u16;
typedef __attribute__((ext_vector_type(8))) short short8;
typedef __attribute__((ext_vector_type(4))) float f32x4;

// ---- bf16 helpers ----
__device__ __forceinline__ u16 f2bf(float x) {           // RNE
    unsigned int u = __float_as_uint(x);
    u += 0x7fffu + ((u >> 16) & 1u);
    return (u16)(u >> 16);
}
__device__ __forceinline__ u16 f2bf_trunc(float x) {     // truncate (1 op)
    return (u16)(__float_as_uint(x) >> 16);
}
__device__ __forceinline__ float bf2f(u16 h) {
    return __uint_as_float(((unsigned int)h) << 16);
}

// ---------------------------------------------------------------- gdiag
__global__ void gdiag_kernel(const float* __restrict__ A,
                             const float* __restrict__ log_lambda,
                             float* __restrict__ gdiag) {
    int id = blockIdx.x * 256 + threadIdx.x;
    if (id >= NHEAD * HDIM) return;
    int h = id >> 6, d = id & 63;
    float s = 0.f;
#pragma unroll
    for (int i = 0; i < 16; ++i) {
        float a = A[(h * 16 + i) * HDIM + d];
        s += a * a;
    }
    gdiag[id] = (s + __expf(log_lambda[h])) * 1.4426950408889634f;
}

// ---------------------------------------------------------------- prep: fp32 -> bf16 hi/lo
__global__ void prep_split(const float* __restrict__ x,
                           const float* __restrict__ Wq, const float* __restrict__ Wk,
                           const float* __restrict__ Wv, const float* __restrict__ Wo,
                           u16* __restrict__ xh, u16* __restrict__ xl,
                           u16* __restrict__ wqh, u16* __restrict__ wql,
                           u16* __restrict__ wkh, u16* __restrict__ wkl,
                           u16* __restrict__ wvh, u16* __restrict__ woh) {
    int seg = blockIdx.y;
    int i = blockIdx.x * 256 + threadIdx.x;   // float4 index
    const float* src; u16* dh; u16* dl; int n4;
    if      (seg == 0) { src = x;  dh = xh;  dl = xl;      n4 = NROWS * D_MODEL / 4; }
    else if (seg == 1) { src = Wq; dh = wqh; dl = wql;     n4 = D_MODEL * D_MODEL / 4; }
    else if (seg == 2) { src = Wk; dh = wkh; dl = wkl;     n4 = D_MODEL * D_MODEL / 4; }
    else if (seg == 3) { src = Wv; dh = wvh; dl = nullptr; n4 = D_MODEL * D_MODEL / 4; }
    else               { src = Wo; dh = woh; dl = nullptr; n4 = D_MODEL * D_MODEL / 4; }
    if (i >= n4) return;
    float4 v = *(const float4*)&src[(size_t)i * 4];
    float vv[4] = {v.x, v.y, v.z, v.w};
    u16 hv[4], lv[4];
#pragma unroll
    for (int j = 0; j < 4; ++j) {
        u16 hb = f2bf(vv[j]);
        hv[j] = hb;
        lv[j] = f2bf(vv[j] - bf2f(hb));
    }
    *(uint2*)&dh[(size_t)i * 4] = *(uint2*)hv;
    if (dl) *(uint2*)&dl[(size_t)i * 4] = *(uint2*)lv;
}

// ---------------------------------------------------------------- MFMA NT GEMM (LDS-staged, R3 version)
template<int NP3>
__global__ __launch_bounds__(256)
void gemm_mfma(const u16* __restrict__ Ah, const u16* __restrict__ Al,
               const u16* __restrict__ BhA, const u16* __restrict__ BlA, const float* __restrict__ biasA,
               float* outfA, u16* auxhA, u16* auxlA, float* ksumA,
               const u16* __restrict__ BhB, const u16* __restrict__ BlB, const float* __restrict__ biasB,
               float* outfB, u16* auxhB, u16* auxlB, float* ksumB,
               int out_layout) {
    const int z = blockIdx.z;
    const u16* Bh = (z == 0) ? BhA : BhB;
    const u16* Bl = (z == 0) ? BlA : BlB;
    const float* bias = (z == 0) ? biasA : biasB;
    float* outf = (z == 0) ? outfA : outfB;
    u16* auxh   = (z == 0) ? auxhA : auxhB;
    u16* auxl   = (z == 0) ? auxlA : auxlB;
    float* ksump= (z == 0) ? ksumA : ksumB;

    __shared__ __align__(16) u16 As_h[128][40], Bs_h[128][40];
    __shared__ __align__(16) u16 As_l[NP3 ? 128 : 1][40], Bs_l[NP3 ? 128 : 1][40];

    const int tid = threadIdx.x;
    const int w = tid >> 6, lane = tid & 63, quad = lane >> 4, n16 = lane & 15;
    const int rBase = blockIdx.y * 128;
    const int cBase = blockIdx.x * 128;

    f32x4 acc[2][8] = {};

    for (int kt = 0; kt < D_MODEL; kt += 32) {
#pragma unroll
        for (int s = 0; s < 2; ++s) {
            int id = s * 256 + tid;          // 512 chunks of 8 bf16
            int row = id >> 2;
            int c8 = (id & 3) * 8;
            *(short8*)&As_h[row][c8] = *(const short8*)&Ah[(size_t)(rBase + row) * D_MODEL + kt + c8];
            *(short8*)&Bs_h[row][c8] = *(const short8*)&Bh[(size_t)(cBase + row) * D_MODEL + kt + c8];
            if (NP3) {
                *(short8*)&As_l[row][c8] = *(const short8*)&Al[(size_t)(rBase + row) * D_MODEL + kt + c8];
                *(short8*)&Bs_l[row][c8] = *(const short8*)&Bl[(size_t)(cBase + row) * D_MODEL + kt + c8];
            }
        }
        __syncthreads();

        short8 a_h[2], a_l[2];
#pragma unroll
        for (int mt = 0; mt < 2; ++mt) {
            a_h[mt] = *(const short8*)&As_h[w * 32 + mt * 16 + n16][quad * 8];
            if (NP3) a_l[mt] = *(const short8*)&As_l[w * 32 + mt * 16 + n16][quad * 8];
        }
#pragma unroll
        for (int nt = 0; nt < 8; ++nt) {
            short8 b_h = *(const short8*)&Bs_h[nt * 16 + n16][quad * 8];
            short8 b_l;
            if (NP3) b_l = *(const short8*)&Bs_l[nt * 16 + n16][quad * 8];
#pragma unroll
            for (int mt = 0; mt < 2; ++mt) {
                acc[mt][nt] = __builtin_amdgcn_mfma_f32_16x16x32_bf16(a_h[mt], b_h, acc[mt][nt], 0, 0, 0);
                if (NP3) {
                    acc[mt][nt] = __builtin_amdgcn_mfma_f32_16x16x32_bf16(a_h[mt], b_l, acc[mt][nt], 0, 0, 0);
                    acc[mt][nt] = __builtin_amdgcn_mfma_f32_16x16x32_bf16(a_l[mt], b_h, acc[mt][nt], 0, 0, 0);
                }
            }
        }
        __syncthreads();
    }

    float csum[8];
#pragma unroll
    for (int nt = 0; nt < 8; ++nt) csum[nt] = 0.f;
#pragma unroll
    for (int mt = 0; mt < 2; ++mt) {
#pragma unroll
        for (int nt = 0; nt < 8; ++nt) {
            int c = cBase + nt * 16 + n16;
            float bc = bias[c];
            int rb = rBase + w * 32 + mt * 16 + quad * 4;
#pragma unroll
            for (int reg = 0; reg < 4; ++reg) {
                float val = acc[mt][nt][reg] + bc;
                int rr = rb + reg;
                size_t idx = out_layout
                    ? ((size_t)(((rr >> 11) * NHEAD + (c >> 6)) * SEQ + (rr & (SEQ - 1)))) * HDIM + (c & 63)
                    : (size_t)rr * D_MODEL + c;
                if (outf) outf[idx] = val;
                if (auxh) {
                    u16 hb = f2bf(val);
                    auxh[idx] = hb;
                    if (auxl) auxl[idx] = f2bf(val - bf2f(hb));
                }
                csum[nt] += val;
            }
        }
    }
    if (ksump) {
#pragma unroll
        for (int nt = 0; nt < 8; ++nt) {
            float cs = csum[nt];
            cs += __shfl_xor(cs, 16);
            cs += __shfl_xor(cs, 32);
            if (quad == 0) {
                int c = cBase + nt * 16 + n16;
                int bb = rBase >> 11;
                atomicAdd(&ksump[(bb * NHEAD + (c >> 6)) * HDIM + (c & 63)], cs);
            }
        }
    }
}

// ---------------------------------------------------------------- v transpose: (b,h,t,hd) bf16 -> (b,h,hd,t)
__global__ __launch_bounds__(256)
void vtrans_kernel(const u16* __restrict__ vh, u16* __restrict__ vT) {
    __shared__ __align__(16) u16 tile[64][72];
    const int tid = threadIdx.x;
    const int t0 = blockIdx.x * 64;
    const int bh = blockIdx.y;
    const u16* vp = vh + (size_t)bh * SEQ * HDIM;
#pragma unroll
    for (int s = 0; s < 2; ++s) {
        int id = s * 256 + tid;
        int row = id >> 3, c8 = (id & 7) * 8;
        *(short8*)&tile[row][c8] = *(const short8*)&vp[(size_t)(t0 + row) * HDIM + c8];
    }
    __syncthreads();
#pragma unroll
    for (int s = 0; s < 2; ++s) {
        int id = s * 256 + tid;
        int d = id >> 3, t8 = (id & 7) * 8;
        short8 r;
#pragma unroll
        for (int i = 0; i < 8; ++i) r[i] = (short)tile[t8 + i][d];
        *(short8*)&vT[((size_t)bh * HDIM + d) * SEQ + t0 + t8] = r;
    }
}

// ---------------------------------------------------------------- flash v6: two-pass, j-split, XCD-swizzled
// Grid = 1024 flat blocks. Decode puts all 32 q-tiles of one head on one XCD
// (dispatch round-robin: xcd = flat & 7), consecutively dispatched, so the
// head's K/V (~768 KB) stays L2-resident on that XCD.
__global__ __launch_bounds__(256)
void flash_v6(const float* __restrict__ q, const u16* __restrict__ kh,
              const u16* __restrict__ kl, const u16* __restrict__ vT,
              const float* __restrict__ ksum, const float* __restrict__ gdiag,
              u16* __restrict__ o) {
    __shared__ __align__(16) u16 ps_all[4 * 64 * 40];   // per-wave p tiles; reused as Os[64][68] f32
    __shared__ float Mw[4][64];
    __shared__ float Lw[4][64];

    const int tid = threadIdx.x;
    const int w = tid >> 6, lane = tid & 63, quad = lane >> 4, n16 = lane & 15;

    // ---- XCD/head swizzle ----
    const int flat = blockIdx.x;          // 0..1023
    const int xcd  = flat & 7;
    const int lidx = flat >> 3;           // 0..127
    const int gh   = xcd + (lidx >> 5) * 8;   // global head 0..31, pinned to xcd
    const int qt   = lidx & 31;
    const int h = gh & (NHEAD - 1), b = gh >> 4;
    const int t0 = qt * 64;

    const size_t bh = (size_t)b * NHEAD + h;
    const float* qp = q + bh * SEQ * HDIM;
    const u16* khp = kh + bh * SEQ * HDIM;
    const u16* klp = kl + bh * SEQ * HDIM;
    const u16* vtp = vT + bh * HDIM * SEQ;
    u16* psw = ps_all + w * 64 * 40;

    // ---- Sg A-fragments (hi/lo): 64 rows x 64 dims; A[m=n16][k=quad*8+j] ----
    short8 sgh[4][2], sgl[4][2];
#pragma unroll
    for (int mt = 0; mt < 4; ++mt) {
#pragma unroll
        for (int kc = 0; kc < 2; ++kc) {
            int row = t0 + mt * 16 + n16;
            int d0 = kc * 32 + quad * 8;
            float4 q0 = *(const float4*)&qp[(size_t)row * HDIM + d0];
            float4 q1 = *(const float4*)&qp[(size_t)row * HDIM + d0 + 4];
            float4 k0 = *(const float4*)&ksum[bh * HDIM + d0];
            float4 k1 = *(const float4*)&ksum[bh * HDIM + d0 + 4];
            float4 g0 = *(const float4*)&gdiag[(size_t)h * HDIM + d0];
            float4 g1 = *(const float4*)&gdiag[(size_t)h * HDIM + d0 + 4];
            float sg[8];
            sg[0] = (2048.f * q0.x - k0.x) * g0.x; sg[1] = (2048.f * q0.y - k0.y) * g0.y;
            sg[2] = (2048.f * q0.z - k0.z) * g0.z; sg[3] = (2048.f * q0.w - k0.w) * g0.w;
            sg[4] = (2048.f * q1.x - k1.x) * g1.x; sg[5] = (2048.f * q1.y - k1.y) * g1.y;
            sg[6] = (2048.f * q1.z - k1.z) * g1.z; sg[7] = (2048.f * q1.w - k1.w) * g1.w;
#pragma unroll
            for (int j = 0; j < 8; ++j) {
                u16 hb = f2bf(sg[j]);
                sgh[mt][kc][j] = (short)hb;
                sgl[mt][kc][j] = (short)f2bf(sg[j] - bf2f(hb));
            }
        }
    }

    float mx[16];
#pragma unroll
    for (int i = 0; i < 16; ++i) mx[i] = -INFINITY;

    // ================= PASS 1: row max (hi-only QK) =================
    for (int it = 0; it < 16; ++it) {
        int jw = it * 128 + w * 32;
        short8 kf[2][2];
#pragma unroll
        for (int kc = 0; kc < 2; ++kc)
#pragma unroll
            for (int ntj = 0; ntj < 2; ++ntj)
                kf[kc][ntj] = *(const short8*)&khp[(size_t)(jw + ntj * 16 + n16) * HDIM + kc * 32 + quad * 8];
        f32x4 lg[2][4] = {};
#pragma unroll
        for (int kc = 0; kc < 2; ++kc)
#pragma unroll
            for (int ntj = 0; ntj < 2; ++ntj)
#pragma unroll
                for (int mt = 0; mt < 4; ++mt)
                    lg[ntj][mt] = __builtin_amdgcn_mfma_f32_16x16x32_bf16(sgh[mt][kc], kf[kc][ntj], lg[ntj][mt], 0, 0, 0);
#pragma unroll
        for (int ntj = 0; ntj < 2; ++ntj)
#pragma unroll
            for (int mt = 0; mt < 4; ++mt)
#pragma unroll
                for (int r = 0; r < 4; ++r)
                    mx[mt * 4 + r] = fmaxf(mx[mt * 4 + r], lg[ntj][mt][r]);
    }

    // ---- merge row max across lanes and waves -> block-common M ----
#pragma unroll
    for (int i = 0; i < 16; ++i) {
        float v = mx[i];
        v = fmaxf(v, __shfl_xor(v, 1));
        v = fmaxf(v, __shfl_xor(v, 2));
        v = fmaxf(v, __shfl_xor(v, 4));
        v = fmaxf(v, __shfl_xor(v, 8));
        mx[i] = v;
    }
    if (n16 == 0) {
#pragma unroll
        for (int mt = 0; mt < 4; ++mt)
#pragma unroll
            for (int r = 0; r < 4; ++r)
                Mw[w][mt * 16 + quad * 4 + r] = mx[mt * 4 + r];
    }
    __syncthreads();
#pragma unroll
    for (int mt = 0; mt < 4; ++mt)
#pragma unroll
        for (int r = 0; r < 4; ++r) {
            int m = mt * 16 + quad * 4 + r;
            mx[mt * 4 + r] = fmaxf(fmaxf(Mw[0][m], Mw[1][m]), fmaxf(Mw[2][m], Mw[3][m]));
        }

    // ================= PASS 2: fixed-M softmax + PV =================
    f32x4 oacc[4][4] = {};   // [mt][ntd]
    f32x4 lacc[4] = {};      // l via ones-MFMA accumulation
    short8 ones;
#pragma unroll
    for (int j = 0; j < 8; ++j) ones[j] = (short)0x3F80;

    for (int it = 0; it < 16; ++it) {
        int jw = it * 128 + w * 32;
        short8 kfh[2][2], kfl[2][2];
#pragma unroll
        for (int kc = 0; kc < 2; ++kc)
#pragma unroll
            for (int ntj = 0; ntj < 2; ++ntj) {
                size_t off = (size_t)(jw + ntj * 16 + n16) * HDIM + kc * 32 + quad * 8;
                kfh[kc][ntj] = *(const short8*)&khp[off];
                kfl[kc][ntj] = *(const short8*)&klp[off];
            }
        short8 bv[4];
#pragma unroll
        for (int ntd = 0; ntd < 4; ++ntd)
            bv[ntd] = *(const short8*)&vtp[(size_t)(ntd * 16 + n16) * SEQ + jw + quad * 8];

        f32x4 lg[2][4] = {};
#pragma unroll
        for (int kc = 0; kc < 2; ++kc)
#pragma unroll
            for (int ntj = 0; ntj < 2; ++ntj)
#pragma unroll
                for (int mt = 0; mt < 4; ++mt) {
                    lg[ntj][mt] = __builtin_amdgcn_mfma_f32_16x16x32_bf16(sgh[mt][kc], kfh[kc][ntj], lg[ntj][mt], 0, 0, 0);
                    lg[ntj][mt] = __builtin_amdgcn_mfma_f32_16x16x32_bf16(sgh[mt][kc], kfl[kc][ntj], lg[ntj][mt], 0, 0, 0);
                    lg[ntj][mt] = __builtin_amdgcn_mfma_f32_16x16x32_bf16(sgl[mt][kc], kfh[kc][ntj], lg[ntj][mt], 0, 0, 0);
                }
        // p = exp2(lg - M); fully independent iterations
#pragma unroll
        for (int mt = 0; mt < 4; ++mt)
#pragma unroll
            for (int r = 0; r < 4; ++r) {
                float M = mx[mt * 4 + r];
                float p0 = exp2f(lg[0][mt][r] - M);
                float p1 = exp2f(lg[1][mt][r] - M);
                int m = mt * 16 + quad * 4 + r;
                psw[m * 40 + n16]      = f2bf_trunc(p0);
                psw[m * 40 + 16 + n16] = f2bf_trunc(p1);
            }
        // PV + l (same-wave DS write->read is in-order)
#pragma unroll
        for (int mt = 0; mt < 4; ++mt) {
            short8 pa = *(const short8*)&psw[(mt * 16 + n16) * 40 + quad * 8];
            lacc[mt] = __builtin_amdgcn_mfma_f32_16x16x32_bf16(pa, ones, lacc[mt], 0, 0, 0);
#pragma unroll
            for (int ntd = 0; ntd < 4; ++ntd)
                oacc[mt][ntd] = __builtin_amdgcn_mfma_f32_16x16x32_bf16(pa, bv[ntd], oacc[mt][ntd], 0, 0, 0);
        }
    }

    // ---- merge waves: common M so plain sums ----
    if (n16 == 0) {
#pragma unroll
        for (int mt = 0; mt < 4; ++mt)
#pragma unroll
            for (int r = 0; r < 4; ++r)
                Lw[w][mt * 16 + quad * 4 + r] = lacc[mt][r];
    }
    __syncthreads();   // Lw ready; all psw reads done (safe to alias Os)

    float* Os = (float*)ps_all;   // [64][68]
#pragma unroll
    for (int ww = 0; ww < 4; ++ww) {
        if (w == ww) {
#pragma unroll
            for (int mt = 0; mt < 4; ++mt)
#pragma unroll
                for (int ntd = 0; ntd < 4; ++ntd)
#pragma unroll
                    for (int r = 0; r < 4; ++r) {
                        int m = mt * 16 + quad * 4 + r;
                        int c = ntd * 16 + n16;
                        float val = oacc[mt][ntd][r];
                        if (ww == 0) Os[m * 68 + c] = val;
                        else         Os[m * 68 + c] += val;
                    }
        }
        __syncthreads();
    }

    // ---- normalize + write bf16 (b, t, h*64+d) ----
    {
        int orow = tid >> 2;
        int c0 = (tid & 3) * 16;
        float inv = 1.f / (((Lw[0][orow] + Lw[1][orow]) + (Lw[2][orow] + Lw[3][orow])));
        u16 outv[16];
#pragma unroll
        for (int cc = 0; cc < 16; ++cc)
            outv[cc] = f2bf(Os[orow * 68 + c0 + cc] * inv);
        u16* dst = o + ((size_t)(b * SEQ + t0 + orow)) * D_MODEL + h * HDIM + c0;
        *(uint4*)dst = *(uint4*)outv;
        *(uint4*)(dst + 8) = *(uint4*)(outv + 8);
    }
}

// ---------------------------------------------------------------- launcher
extern "C" void kernel_launch(void* const* d_in, const int* in_sizes, int n_in,
                              void* d_out, int out_size, void* d_ws, size_t ws_size,
                              hipStream_t stream) {
    const float* x  = (const float*)d_in[0];
    const float* Wq = (const float*)d_in[1];
    const float* bq = (const float*)d_in[2];
    const float* Wk = (const float*)d_in[3];
    const float* bk = (const float*)d_in[4];
    const float* Wv = (const float*)d_in[5];
    const float* bv = (const float*)d_in[6];
    const float* Wo = (const float*)d_in[7];
    const float* bo = (const float*)d_in[8];
    const float* A  = (const float*)d_in[9];
    const float* ll = (const float*)d_in[10];
    float* out = (float*)d_out;

    const size_t NQKV = (size_t)NROWS * D_MODEL;   // 4,194,304
    const size_t NW = (size_t)D_MODEL * D_MODEL;   // 1,048,576
    char* base = (char*)d_ws;
    float* q_ws = (float*)base;            base += NQKV * 4;
    u16* xh  = (u16*)base;                 base += NQKV * 2;   // reused as o_hi after QKV
    u16* xl  = (u16*)base;                 base += NQKV * 2;   // reused as vT after QKV
    u16* khw = (u16*)base;                 base += NQKV * 2;
    u16* klw = (u16*)base;                 base += NQKV * 2;
    u16* vhw = (u16*)base;                 base += NQKV * 2;
    u16* wqh = (u16*)base;                 base += NW * 2;
    u16* wql = (u16*)base;                 base += NW * 2;
    u16* wkh = (u16*)base;                 base += NW * 2;
    u16* wkl = (u16*)base;                 base += NW * 2;
    u16* wvh = (u16*)base;                 base += NW * 2;
    u16* woh = (u16*)base;                 base += NW * 2;
    float* gd_ws   = (float*)base;         base += NHEAD * HDIM * 4;
    float* ksum_ws = (float*)base;         base += BATCH * NHEAD * HDIM * 4;

    hipMemsetAsync(ksum_ws, 0, BATCH * NHEAD * HDIM * sizeof(float), stream);

    prep_split<<<dim3(4096, 5), 256, 0, stream>>>(x, Wq, Wk, Wv, Wo,
                                                  xh, xl, wqh, wql, wkh, wkl, wvh, woh);
    gdiag_kernel<<<4, 256, 0, stream>>>(A, ll, gd_ws);

    // Q (z=0) + K (z=1): 3-pass split-bf16; K writes k_hi/k_lo + ksum atomics
    gemm_mfma<1><<<dim3(8, 32, 2), 256, 0, stream>>>(
        xh, xl,
        wqh, wql, bq, q_ws, nullptr, nullptr, nullptr,
        wkh, wkl, bk, nullptr, khw, klw, ksum_ws,
        1);
    // V: 1-pass bf16
    gemm_mfma<0><<<dim3(8, 32, 1), 256, 0, stream>>>(
        xh, nullptr,
        wvh, nullptr, bv, nullptr, vhw, nullptr, nullptr,
        wvh, nullptr, bv, nullptr, vhw, nullptr, nullptr,
        1);

    u16* vTw = xl;   // alias: x_lo dead after QKV GEMMs
    u16* ohw = xh;   // alias: x_hi dead after QKV GEMMs
    vtrans_kernel<<<dim3(SEQ / 64, BATCH * NHEAD), 256, 0, stream>>>(vhw, vTw);

    flash_v6<<<dim3(SEQ / 64 * NHEAD * BATCH), 256, 0, stream>>>(
        q_ws, khw, klw, vTw, ksum_ws, gd_ws, ohw);

    // out-proj: 1-pass bf16, row-major fp32 output
    gemm_mfma<0><<<dim3(8, 32, 1), 256, 0, stream>>>(
        ohw, nullptr,
        woh, nullptr, bo, out, nullptr, nullptr, nullptr,
        woh, nullptr, bo, out, nullptr, nullptr, nullptr,
        0);
}